// Round 10
// baseline (975.930 us; speedup 1.0000x reference)
//
#include <hip/hip_runtime.h>

// Problem constants
#define NROWS   16384      // 16*32*32 flattened (b,h,w) rows
#define KCODES  8192
#define CDIM    256
#define HWS     1024       // 32*32
#define BSTRIDE 262144     // 256*1024 floats per batch in z / out

// Workspace layout (float-unit offsets) -- 8 slices
#define WS_AN   0                         // ||x||^2 per row       [16384]
#define WS_CE   16384                     // ||e||^2 per code      [8192]
#define WS_CD   24576                     // cand dist [n*8+slice] [131072]
#define WS_CI   155648                    // cand idx  (int)       [131072]
#define WS_IDX  286720                    // final idx (int)       [16384]
#define WS_LOSS 303104                    // loss accumulator      [1]

typedef float f32x2 __attribute__((ext_vector_type(2)));
typedef float f32x4 __attribute__((ext_vector_type(4)));

// v_pk_fma_f32: two independent fp32 FMAs per instruction; measured sustained
// ~4.8 cyc/instr (RF-port bound; r13 step-major reorder was null -> not dep
// latency). Kernel VALU-busy floor ~530us.
// R10 LESSON: (256,3) spilled asm-pair accs. R12 LESSON: prefetch-early
// spilled. R11/R13 LESSON: residency pinned at 2 blocks/CU (=2 waves/SIMD at
// 256 threads) across all LDS/grid configs -> idle ~340us.
// R14: 512-thread blocks. Even at 2 blocks/CU residency that is 16 waves/CU =
// 4 waves/SIMD (2x latency hiding). Per-thread acc halves to 64 VGPR so the
// (512,4) cap of 128 VGPR fits. Same tiles, same LDS layouts, bit-exact math.
#define PKFMA_LO(acc, a, b) \
  asm("v_pk_fma_f32 %0, %1, %2, %0 op_sel:[0,0,0] op_sel_hi:[0,1,1]" \
      : "+v"(acc) : "v"(a), "v"(b))
#define PKFMA_HI(acc, a, b) \
  asm("v_pk_fma_f32 %0, %1, %2, %0 op_sel:[1,0,0] op_sel_hi:[1,1,1]" \
      : "+v"(acc) : "v"(a), "v"(b))

// -------- row norms, replicating numpy pairwise_sum order exactly --------
__global__ void rownorm_z_k(const float* __restrict__ z, float* __restrict__ An) {
#pragma clang fp contract(off)
  int n = blockIdx.x * 256 + threadIdx.x;                    // 16384 threads
  const float* base = z + ((size_t)(n >> 10)) * BSTRIDE + (n & 1023);
  float hs[2];
  for (int h = 0; h < 2; ++h) {
    float r[8];
#pragma unroll
    for (int j = 0; j < 8; ++j) { float v = base[(size_t)(h * 128 + j) * HWS]; r[j] = v * v; }
    for (int m = 1; m < 16; ++m) {
#pragma unroll
      for (int j = 0; j < 8; ++j) { float v = base[(size_t)(h * 128 + m * 8 + j) * HWS]; r[j] += v * v; }
    }
    hs[h] = ((r[0] + r[1]) + (r[2] + r[3])) + ((r[4] + r[5]) + (r[6] + r[7]));
  }
  An[n] = hs[0] + hs[1];
}

__global__ void rownorm_e_k(const float* __restrict__ emb, float* __restrict__ Ce) {
#pragma clang fp contract(off)
  int n = blockIdx.x * 256 + threadIdx.x;                    // 8192 threads
  const float* base = emb + (size_t)n * CDIM;
  float hs[2];
  for (int h = 0; h < 2; ++h) {
    float r[8];
#pragma unroll
    for (int j = 0; j < 8; ++j) { float v = base[h * 128 + j]; r[j] = v * v; }
    for (int m = 1; m < 16; ++m) {
#pragma unroll
      for (int j = 0; j < 8; ++j) { float v = base[h * 128 + m * 8 + j]; r[j] += v * v; }
    }
    hs[h] = ((r[0] + r[1]) + (r[2] + r[3])) + ((r[4] + r[5]) + (r[6] + r[7]));
  }
  Ce[n] = hs[0] + hs[1];
}

// -------- fused distance + argmin (round 14: 512-thread blocks) -------------
// 1024 blocks = 128 row-tiles (128 rows) x 8 code-slices (1024 codes each).
// slice = bid&7 -> natural XCD affinity. Block = 16 tx x 16 ty x 2 wz:
// wz splits the 8 ci2 of the 256-code kc-tile (wz=0: ci2' 0..3 = codes
// +0..127-ish interleaved; wz=1: ci2' 4..7). Per-thread 8 rows x 8 codes
// (acc2[8][4], 64 VGPR). Same LDS tiles/layouts as rounds 9-13:
//   A: As[128 rows][32 c], col=((kg^((row>>3)&7))<<2)|wi; conflict-free.
//   B: [128 pairs][32 k][2 codes], granule-swizzled by pair&7; one
//   ds_read_b128 = two packed operands. bB gains +wz*4096.
// Per-(row,code) accumulation order (sc asc, g asc, k3-first 4-k chains) and
// strict-< ascending in-thread compares unchanged; cross-thread merge
// tie-breaks by explicit index -> result identical regardless of partition.
// WRITE_SIZE ~8192 is the no-spill tripwire (r10/r12 spills: 4e6/181K).
__global__ void __launch_bounds__(512, 4)
vq_argmin_k(const float* __restrict__ z, const float* __restrict__ emb,
            const float* __restrict__ An, const float* __restrict__ Ce,
            float* __restrict__ cand_d, int* __restrict__ cand_i) {
  __shared__ float smem[12288];    // 48 KB: As=[0,4096), Bs=[4096,12288)
  float* As = smem;                // [128 rows][32 c], col XOR-swizzled by (row>>3)&7
  float* Bs = smem + 4096;         // [128 pairs][32 k][2 codes], granule-swizzled by pair&7

  const int t  = threadIdx.x;
  const int tx = t & 15;           // code group within wz half
  const int ty = (t >> 4) & 15;    // row group (8 consecutive rows)
  const int wz = t >> 8;           // ci2-range half (0: ci2' 0..3, 1: 4..7)
  const int bid   = blockIdx.x;
  const int slice = bid & 7;       // slice s -> XCD s
  const int tile  = bid >> 3;
  const int rbase = tile * 128;    // never crosses the 1024-hw batch edge
  const int k0    = slice * 1024;

  const float* zb = z + ((size_t)(rbase >> 10)) * BSTRIDE + (rbase & 1023);

  float best[8];
  int   bidx[8];
#pragma unroll
  for (int ri = 0; ri < 8; ++ri) { best[ri] = 3.4028235e38f; bidx[ri] = 0; }

  f32x2 acc2[8][4];                // [ri][ci2]: .x = code tx+32*(ci2+4wz), .y = +16
#pragma unroll
  for (int ri = 0; ri < 8; ++ri)
#pragma unroll
    for (int j = 0; j < 4; ++j) acc2[ri][j] = (f32x2){0.f, 0.f};

  // ---- staging thread mappings (512 threads; half the per-thread volume) ----
  // A: thread stages 1 c-column (a_c = t>>4, 0..31) x 8 rows (a_hw).
  const int a_c   = t >> 4;         // c_local 0..31
  const int a_hw  = (t & 15) * 8;   // 8 consecutive rows
  const int a_swr = (t & 15) & 7;   // (row>>3)&7 for all 8 staged rows
  const int acol  = (((a_c >> 2) ^ a_swr) << 2) | (a_c & 3);   // const per thread
  // B: 4 threads per code row; thread loads 8 consecutive c (b_cb) of code
  // b_code, twice (codes +0 / +128), scatters 4 (k,k+1) pairs per pass.
  const int b_code = t >> 2;        // code 0..127 (pass adds +128)
  const int b_cb   = (t & 3) * 8;   // c_local base 0/8/16/24
  const int b_p    = ((b_code >> 5) << 4) | (b_code & 15); // pair row 0..63
  const int b_s    = (b_code >> 4) & 1;                    // which half of pair
  const int b_p7   = b_code & 7;                           // == pair&7
  const int b_g0   = b_cb >> 1;                            // granule base 0/4/8/12
  const int b_rowb = b_p * 64 + b_s;                       // float units; pass1 += 4096

  const int rd_a_sw = ty & 7;
  const int rd_b_sw = tx & 7;       // == pair&7 for all this thread's pair rows
  const int bBw     = tx * 64 + wz * 4096;  // pair-row base incl. wz half

  for (int kc = 0; kc < 4; ++kc) {
    const int kbase = k0 + kc * 256;
#pragma unroll 1
    for (int sc = 0; sc < 8; ++sc) {
      // short prefetch: issue just before barrier; regs die at the stores
      const float* zsrc = zb + (size_t)(sc * 32 + a_c) * HWS + a_hw;
      const float4 pa0 = *(const float4*)(zsrc);
      const float4 pa1 = *(const float4*)(zsrc + 4);
      const float* bsrc0 = emb + (size_t)(kbase + b_code) * CDIM + sc * 32 + b_cb;
      const float* bsrc1 = bsrc0 + (size_t)128 * CDIM;
      const float4 pb0 = *(const float4*)(bsrc0);
      const float4 pb1 = *(const float4*)(bsrc0 + 4);
      const float4 pb2 = *(const float4*)(bsrc1);
      const float4 pb3 = *(const float4*)(bsrc1 + 4);

      __syncthreads();                      // barrier A: prior compute done
      {
        // A transpose-store: 8 scalar stores, col const per thread (2-way free)
        const float va[8] = {pa0.x, pa0.y, pa0.z, pa0.w, pa1.x, pa1.y, pa1.z, pa1.w};
#pragma unroll
        for (int j = 0; j < 8; ++j) {
          As[((a_hw + j) << 5) + acol] = va[j];
        }
        // B pair-scatter, two passes (codes +0 / +128): 4 (k,k+1) pairs each;
        // stride-2 pairs merge into ds_write2_b32.
        const float bval0[8] = {pb0.x, pb0.y, pb0.z, pb0.w, pb1.x, pb1.y, pb1.z, pb1.w};
        const float bval1[8] = {pb2.x, pb2.y, pb2.z, pb2.w, pb3.x, pb3.y, pb3.z, pb3.w};
#pragma unroll
        for (int i = 0; i < 4; ++i) {
          const int off = b_rowb + (((b_g0 + i) ^ b_p7) << 2);
          Bs[off]            = bval0[2 * i];
          Bs[off + 2]        = bval0[2 * i + 1];
          Bs[off + 4096]     = bval1[2 * i];
          Bs[off + 4096 + 2] = bval1[2 * i + 1];
        }
      }
      __syncthreads();                      // barrier B: staged data visible

      // 8x8 micro-tile over 32 k: 1024 pk_fma, 64 A + 64 B b128 reads.
      // Chain-major (r11 order; r13 step-major was null).
#pragma unroll
      for (int g = 0; g < 8; ++g) {
        f32x4 av[8];
#pragma unroll
        for (int ri = 0; ri < 8; ++ri)
          av[ri] = *(const f32x4*)&As[((ty * 8 + ri) << 5) + ((g ^ rd_a_sw) << 2)];
        const int sw0 = ((2 * g) ^ rd_b_sw) << 2;   // granule 2g   (k 4g,4g+1)
        const int sw1 = sw0 ^ 4;                    // granule 2g+1 (k 4g+2,4g+3)
#pragma unroll
        for (int ci2 = 0; ci2 < 4; ++ci2) {
          const f32x4 b0 = *(const f32x4*)&Bs[bBw + ci2 * 1024 + sw0];
          const f32x4 b1 = *(const f32x4*)&Bs[bBw + ci2 * 1024 + sw1];
          const f32x2 bk0 = __builtin_shufflevector(b0, b0, 0, 1);
          const f32x2 bk1 = __builtin_shufflevector(b0, b0, 2, 3);
          const f32x2 bk2 = __builtin_shufflevector(b1, b1, 0, 1);
          const f32x2 bk3 = __builtin_shufflevector(b1, b1, 2, 3);
#pragma unroll
          for (int ri = 0; ri < 8; ++ri) {
            const f32x2 a01 = __builtin_shufflevector(av[ri], av[ri], 0, 1);
            const f32x2 a23 = __builtin_shufflevector(av[ri], av[ri], 2, 3);
            // 4-k group, k3-first chain: identical lane math to rounds 1-13
            PKFMA_HI(acc2[ri][ci2], a23, bk3);
            PKFMA_LO(acc2[ri][ci2], a23, bk2);
            PKFMA_HI(acc2[ri][ci2], a01, bk1);
            PKFMA_LO(acc2[ri][ci2], a01, bk0);
          }
        }
      }
    }

    // fold per kc: dist = (A - 2*dot) + C with np's elementwise fp32 rounding.
    // in-thread codes ascend with ci2 (.x then .y) -> strict < keeps lowest
    // index within thread; cross-thread/slice merges compare indices.
    {
      const int kkb = kbase + tx + 128 * wz;   // lead code base for this thread
      float cearr[8];
#pragma unroll
      for (int ci2 = 0; ci2 < 4; ++ci2) {
        cearr[2 * ci2]     = Ce[kkb + ci2 * 32];
        cearr[2 * ci2 + 1] = Ce[kkb + ci2 * 32 + 16];
      }
#pragma unroll
      for (int ri = 0; ri < 8; ++ri) {
        const float Ar = An[rbase + ty * 8 + ri];   // reload (saves live regs)
#pragma unroll
        for (int ci2 = 0; ci2 < 4; ++ci2) {
          const float d0 = (Ar - 2.0f * acc2[ri][ci2].x) + cearr[2 * ci2];
          if (d0 < best[ri]) { best[ri] = d0; bidx[ri] = kkb + ci2 * 32; }
          const float d1 = (Ar - 2.0f * acc2[ri][ci2].y) + cearr[2 * ci2 + 1];
          if (d1 < best[ri]) { best[ri] = d1; bidx[ri] = kkb + ci2 * 32 + 16; }
          acc2[ri][ci2] = (f32x2){0.f, 0.f};
        }
      }
    }
  }

  // cross-thread argmin per row (tie -> lower absolute index); alias smem
  __syncthreads();                 // compute done; safe to overwrite As/Bs
  float* redd = smem;              // [128][32]
  int*   redi = (int*)(smem + 4096);
#pragma unroll
  for (int ri = 0; ri < 8; ++ri) {
    redd[(ty * 8 + ri) * 32 + (wz * 16 + tx)] = best[ri];
    redi[(ty * 8 + ri) * 32 + (wz * 16 + tx)] = bidx[ri];
  }
  __syncthreads();
  if (t < 128) {
    float bd = redd[t * 32];
    int   bi = redi[t * 32];
    for (int j = 1; j < 32; ++j) {
      const float d  = redd[t * 32 + j];
      const int   i2 = redi[t * 32 + j];
      if (d < bd || (d == bd && i2 < bi)) { bd = d; bi = i2; }
    }
    const int n = rbase + t;
    cand_d[n * 8 + slice] = bd;
    cand_i[n * 8 + slice] = bi;
  }
}

// -------- merge the 8 code-slices (tie -> lower index) --------
__global__ void vq_merge_k(const float* __restrict__ cand_d, const int* __restrict__ cand_i,
                           int* __restrict__ idx_final, float* __restrict__ idxf_out) {
  const int n = blockIdx.x * 256 + threadIdx.x;   // 16384
  float bd = cand_d[n * 8];
  int   bi = cand_i[n * 8];
#pragma unroll
  for (int s = 1; s < 8; ++s) {
    const float d  = cand_d[n * 8 + s];
    const int   i2 = cand_i[n * 8 + s];
    if (d < bd || (d == bd && i2 < bi)) { bd = d; bi = i2; }
  }
  idx_final[n] = bi;
  idxf_out[n] = (float)bi;
}

// -------- gather quantized, write straight-through output, accumulate loss ----
// quantized_st = z + (q - z) in fp32 (matches np rounding; != q exactly).
__launch_bounds__(256)
__global__ void vq_gather_loss_k(const float* __restrict__ z, const float* __restrict__ emb,
                                 const int* __restrict__ idx_final,
                                 float* __restrict__ qout, float* __restrict__ loss_acc) {
  __shared__ float Qs[32 * 260];
  __shared__ int   kidx[32];
  __shared__ float warp_s[4];
  const int t = threadIdx.x;
  const int rbase = blockIdx.x * 32;
  if (t < 32) kidx[t] = idx_final[rbase + t];
  __syncthreads();
  {
    const int r = t >> 3, cp = t & 7;
    const float4* er = (const float4*)(emb + (size_t)kidx[r] * CDIM);
#pragma unroll
    for (int j = 0; j < 8; ++j) {
      const int c4 = cp + j * 8;
      const float4 v = er[c4];
      *(float4*)&Qs[r * 260 + c4 * 4] = v;
    }
  }
  __syncthreads();
  const int b = rbase >> 10, hw0 = rbase & 1023;
  const float* zb = z + (size_t)b * BSTRIDE + hw0;
  float* qb = qout + (size_t)b * BSTRIDE + hw0;
  float s = 0.f;
  const int hwl = t & 31, cg = t >> 5;
  for (int i = 0; i < 32; ++i) {
    const int c = cg * 32 + i;
    const float q  = Qs[hwl * 260 + c];
    const size_t off = (size_t)c * HWS + hwl;
    const float zv = zb[off];
    const float d  = q - zv;
    qb[off] = zv + d;          // straight-through value, np rounding
    s += d * d;
  }
  for (int off = 32; off; off >>= 1) s += __shfl_down(s, off, 64);
  if ((t & 63) == 0) warp_s[t >> 6] = s;
  __syncthreads();
  if (t == 0) atomicAdd(loss_acc, warp_s[0] + warp_s[1] + warp_s[2] + warp_s[3]);
}

__global__ void vq_finalize_k(const float* __restrict__ loss_acc, float* __restrict__ out_loss) {
  const float m = loss_acc[0] * (1.0f / 4194304.0f);
  out_loss[0] = m;          // codebook_loss
  out_loss[1] = 0.25f * m;  // commitment_loss (BETA * same mean)
}

extern "C" void kernel_launch(void* const* d_in, const int* in_sizes, int n_in,
                              void* d_out, int out_size, void* d_ws, size_t ws_size,
                              hipStream_t stream) {
  (void)in_sizes; (void)n_in; (void)out_size; (void)ws_size;
  const float* z   = (const float*)d_in[0];
  const float* emb = (const float*)d_in[1];
  float* out      = (float*)d_out;
  float* q_out    = out;                 // [16,256,32,32]
  float* loss_out = out + 4194304;       // 2 scalars
  float* idxf_out = out + 4194306;       // [16,32,32] as float

  float* ws       = (float*)d_ws;
  float* An       = ws + WS_AN;
  float* Ce       = ws + WS_CE;
  float* cand_d   = ws + WS_CD;
  int*   cand_i   = (int*)(ws + WS_CI);
  int*   idx_fin  = (int*)(ws + WS_IDX);
  float* loss_acc = ws + WS_LOSS;

  hipMemsetAsync(loss_acc, 0, sizeof(float), stream);
  rownorm_z_k<<<64, 256, 0, stream>>>(z, An);
  rownorm_e_k<<<32, 256, 0, stream>>>(emb, Ce);
  vq_argmin_k<<<1024, 512, 0, stream>>>(z, emb, An, Ce, cand_d, cand_i);
  vq_merge_k<<<64, 256, 0, stream>>>(cand_d, cand_i, idx_fin, idxf_out);
  vq_gather_loss_k<<<512, 256, 0, stream>>>(z, emb, idx_fin, q_out, loss_acc);
  vq_finalize_k<<<1, 1, 0, stream>>>(loss_acc, loss_out);
}

// Round 12
// 909.404 us; speedup vs baseline: 1.0732x; 1.0732x over previous
//
#include <hip/hip_runtime.h>

// Problem constants
#define NROWS   16384      // 16*32*32 flattened (b,h,w) rows
#define KCODES  8192
#define CDIM    256
#define HWS     1024       // 32*32
#define BSTRIDE 262144     // 256*1024 floats per batch in z / out

// Workspace layout (float-unit offsets) -- 8 slices
#define WS_AN   0                         // ||x||^2 per row       [16384]
#define WS_CE   16384                     // ||e||^2 per code      [8192]
#define WS_CD   24576                     // cand dist [n*8+slice] [131072]
#define WS_CI   155648                    // cand idx  (int)       [131072]
#define WS_IDX  286720                    // final idx (int)       [16384]
#define WS_LOSS 303104                    // loss accumulator      [1]

typedef float f32x2 __attribute__((ext_vector_type(2)));
typedef float f32x4 __attribute__((ext_vector_type(4)));

// v_pk_fma_f32: two independent fp32 FMAs per instruction; measured sustained
// ~4.8 cyc/instr (RF-port bound; r13 step-major was null). VALU floor ~530us.
// LAUNCH-BOUNDS RULE (measured r10/r14): VGPR cap ~= 256 / min_waves_arg,
// independent of block size. (256,3)->84, (512,4)->64 (spilled: WRITE_SIZE
// 8192->204K). (x,2)->~128: the budget r9/r11 compiled clean at 124.
// R14 LESSON (the win): 512-thread blocks DOUBLE occupancy (21->40.5%) -- the
// residency cap was block-count-based. R15 = r14 structure + (512,2) so the
// occupancy gain arrives without the spill.
#define PKFMA_LO(acc, a, b) \
  asm("v_pk_fma_f32 %0, %1, %2, %0 op_sel:[0,0,0] op_sel_hi:[0,1,1]" \
      : "+v"(acc) : "v"(a), "v"(b))
#define PKFMA_HI(acc, a, b) \
  asm("v_pk_fma_f32 %0, %1, %2, %0 op_sel:[1,0,0] op_sel_hi:[1,1,1]" \
      : "+v"(acc) : "v"(a), "v"(b))

// -------- row norms, replicating numpy pairwise_sum order exactly --------
__global__ void rownorm_z_k(const float* __restrict__ z, float* __restrict__ An) {
#pragma clang fp contract(off)
  int n = blockIdx.x * 256 + threadIdx.x;                    // 16384 threads
  const float* base = z + ((size_t)(n >> 10)) * BSTRIDE + (n & 1023);
  float hs[2];
  for (int h = 0; h < 2; ++h) {
    float r[8];
#pragma unroll
    for (int j = 0; j < 8; ++j) { float v = base[(size_t)(h * 128 + j) * HWS]; r[j] = v * v; }
    for (int m = 1; m < 16; ++m) {
#pragma unroll
      for (int j = 0; j < 8; ++j) { float v = base[(size_t)(h * 128 + m * 8 + j) * HWS]; r[j] += v * v; }
    }
    hs[h] = ((r[0] + r[1]) + (r[2] + r[3])) + ((r[4] + r[5]) + (r[6] + r[7]));
  }
  An[n] = hs[0] + hs[1];
}

__global__ void rownorm_e_k(const float* __restrict__ emb, float* __restrict__ Ce) {
#pragma clang fp contract(off)
  int n = blockIdx.x * 256 + threadIdx.x;                    // 8192 threads
  const float* base = emb + (size_t)n * CDIM;
  float hs[2];
  for (int h = 0; h < 2; ++h) {
    float r[8];
#pragma unroll
    for (int j = 0; j < 8; ++j) { float v = base[h * 128 + j]; r[j] = v * v; }
    for (int m = 1; m < 16; ++m) {
#pragma unroll
      for (int j = 0; j < 8; ++j) { float v = base[h * 128 + m * 8 + j]; r[j] += v * v; }
    }
    hs[h] = ((r[0] + r[1]) + (r[2] + r[3])) + ((r[4] + r[5]) + (r[6] + r[7]));
  }
  Ce[n] = hs[0] + hs[1];
}

// -------- fused distance + argmin (round 15: 512 threads, (512,2)) ----------
// 1024 blocks = 128 row-tiles (128 rows) x 8 code-slices (1024 codes each).
// slice = bid&7 -> natural XCD affinity. Block = 16 tx x 16 ty x 2 wz:
// wz splits the 8 ci2 of the 256-code kc-tile. Per-thread 8 rows x 8 codes
// (acc2[8][4], 64 VGPR). Same LDS tiles/layouts as rounds 9-14:
//   A: As[128 rows][32 c], col=((kg^((row>>3)&7))<<2)|wi; conflict-free.
//   B: [128 pairs][32 k][2 codes], granule-swizzled by pair&7; one
//   ds_read_b128 = two packed operands. bB gains +wz*4096.
// Per-(row,code) accumulation order (sc asc, g asc, k3-first 4-k chains) and
// strict-< ascending in-thread compares unchanged; cross-thread merge
// tie-breaks by explicit index -> result identical regardless of partition.
// WRITE_SIZE ~8192 is the no-spill tripwire (r10/r12/r14: 4e6/181K/204K).
__global__ void __launch_bounds__(512, 2)
vq_argmin_k(const float* __restrict__ z, const float* __restrict__ emb,
            const float* __restrict__ An, const float* __restrict__ Ce,
            float* __restrict__ cand_d, int* __restrict__ cand_i) {
  __shared__ float smem[12288];    // 48 KB: As=[0,4096), Bs=[4096,12288)
  float* As = smem;                // [128 rows][32 c], col XOR-swizzled by (row>>3)&7
  float* Bs = smem + 4096;         // [128 pairs][32 k][2 codes], granule-swizzled by pair&7

  const int t  = threadIdx.x;
  const int tx = t & 15;           // code group within wz half
  const int ty = (t >> 4) & 15;    // row group (8 consecutive rows)
  const int wz = t >> 8;           // ci2-range half (0: ci2' 0..3, 1: 4..7)
  const int bid   = blockIdx.x;
  const int slice = bid & 7;       // slice s -> XCD s
  const int tile  = bid >> 3;
  const int rbase = tile * 128;    // never crosses the 1024-hw batch edge
  const int k0    = slice * 1024;

  const float* zb = z + ((size_t)(rbase >> 10)) * BSTRIDE + (rbase & 1023);

  float best[8];
  int   bidx[8];
#pragma unroll
  for (int ri = 0; ri < 8; ++ri) { best[ri] = 3.4028235e38f; bidx[ri] = 0; }

  f32x2 acc2[8][4];                // [ri][ci2]: .x = code tx+32*(ci2+4wz), .y = +16
#pragma unroll
  for (int ri = 0; ri < 8; ++ri)
#pragma unroll
    for (int j = 0; j < 4; ++j) acc2[ri][j] = (f32x2){0.f, 0.f};

  // ---- staging thread mappings (512 threads; half the per-thread volume) ----
  // A: thread stages 1 c-column (a_c = t>>4, 0..31) x 8 rows (a_hw).
  const int a_c   = t >> 4;         // c_local 0..31
  const int a_hw  = (t & 15) * 8;   // 8 consecutive rows
  const int a_swr = (t & 15) & 7;   // (row>>3)&7 for all 8 staged rows
  const int acol  = (((a_c >> 2) ^ a_swr) << 2) | (a_c & 3);   // const per thread
  // B: 4 threads per code row; thread loads 8 consecutive c (b_cb) of code
  // b_code, twice (codes +0 / +128), scatters 4 (k,k+1) pairs per pass.
  const int b_code = t >> 2;        // code 0..127 (pass adds +128)
  const int b_cb   = (t & 3) * 8;   // c_local base 0/8/16/24
  const int b_p    = ((b_code >> 5) << 4) | (b_code & 15); // pair row 0..63
  const int b_s    = (b_code >> 4) & 1;                    // which half of pair
  const int b_p7   = b_code & 7;                           // == pair&7
  const int b_g0   = b_cb >> 1;                            // granule base 0/4/8/12
  const int b_rowb = b_p * 64 + b_s;                       // float units; pass1 += 4096

  const int rd_a_sw = ty & 7;
  const int rd_b_sw = tx & 7;       // == pair&7 for all this thread's pair rows
  const int bBw     = tx * 64 + wz * 4096;  // pair-row base incl. wz half

  for (int kc = 0; kc < 4; ++kc) {
    const int kbase = k0 + kc * 256;
#pragma unroll 1
    for (int sc = 0; sc < 8; ++sc) {
      // short prefetch: issue just before barrier; regs die at the stores
      const float* zsrc = zb + (size_t)(sc * 32 + a_c) * HWS + a_hw;
      const float4 pa0 = *(const float4*)(zsrc);
      const float4 pa1 = *(const float4*)(zsrc + 4);
      const float* bsrc0 = emb + (size_t)(kbase + b_code) * CDIM + sc * 32 + b_cb;
      const float* bsrc1 = bsrc0 + (size_t)128 * CDIM;
      const float4 pb0 = *(const float4*)(bsrc0);
      const float4 pb1 = *(const float4*)(bsrc0 + 4);
      const float4 pb2 = *(const float4*)(bsrc1);
      const float4 pb3 = *(const float4*)(bsrc1 + 4);

      __syncthreads();                      // barrier A: prior compute done
      {
        // A transpose-store: 8 scalar stores, col const per thread (2-way free)
        const float va[8] = {pa0.x, pa0.y, pa0.z, pa0.w, pa1.x, pa1.y, pa1.z, pa1.w};
#pragma unroll
        for (int j = 0; j < 8; ++j) {
          As[((a_hw + j) << 5) + acol] = va[j];
        }
        // B pair-scatter, two passes (codes +0 / +128): 4 (k,k+1) pairs each;
        // stride-2 pairs merge into ds_write2_b32.
        const float bval0[8] = {pb0.x, pb0.y, pb0.z, pb0.w, pb1.x, pb1.y, pb1.z, pb1.w};
        const float bval1[8] = {pb2.x, pb2.y, pb2.z, pb2.w, pb3.x, pb3.y, pb3.z, pb3.w};
#pragma unroll
        for (int i = 0; i < 4; ++i) {
          const int off = b_rowb + (((b_g0 + i) ^ b_p7) << 2);
          Bs[off]            = bval0[2 * i];
          Bs[off + 2]        = bval0[2 * i + 1];
          Bs[off + 4096]     = bval1[2 * i];
          Bs[off + 4096 + 2] = bval1[2 * i + 1];
        }
      }
      __syncthreads();                      // barrier B: staged data visible

      // 8x8 micro-tile over 32 k: 1024 pk_fma, 64 A + 64 B b128 reads.
      // Chain-major (r11 order; r13 step-major was null).
#pragma unroll
      for (int g = 0; g < 8; ++g) {
        f32x4 av[8];
#pragma unroll
        for (int ri = 0; ri < 8; ++ri)
          av[ri] = *(const f32x4*)&As[((ty * 8 + ri) << 5) + ((g ^ rd_a_sw) << 2)];
        const int sw0 = ((2 * g) ^ rd_b_sw) << 2;   // granule 2g   (k 4g,4g+1)
        const int sw1 = sw0 ^ 4;                    // granule 2g+1 (k 4g+2,4g+3)
#pragma unroll
        for (int ci2 = 0; ci2 < 4; ++ci2) {
          const f32x4 b0 = *(const f32x4*)&Bs[bBw + ci2 * 1024 + sw0];
          const f32x4 b1 = *(const f32x4*)&Bs[bBw + ci2 * 1024 + sw1];
          const f32x2 bk0 = __builtin_shufflevector(b0, b0, 0, 1);
          const f32x2 bk1 = __builtin_shufflevector(b0, b0, 2, 3);
          const f32x2 bk2 = __builtin_shufflevector(b1, b1, 0, 1);
          const f32x2 bk3 = __builtin_shufflevector(b1, b1, 2, 3);
#pragma unroll
          for (int ri = 0; ri < 8; ++ri) {
            const f32x2 a01 = __builtin_shufflevector(av[ri], av[ri], 0, 1);
            const f32x2 a23 = __builtin_shufflevector(av[ri], av[ri], 2, 3);
            // 4-k group, k3-first chain: identical lane math to rounds 1-14
            PKFMA_HI(acc2[ri][ci2], a23, bk3);
            PKFMA_LO(acc2[ri][ci2], a23, bk2);
            PKFMA_HI(acc2[ri][ci2], a01, bk1);
            PKFMA_LO(acc2[ri][ci2], a01, bk0);
          }
        }
      }
    }

    // fold per kc: dist = (A - 2*dot) + C with np's elementwise fp32 rounding.
    // in-thread codes ascend with ci2 (.x then .y) -> strict < keeps lowest
    // index within thread; cross-thread/slice merges compare indices.
    {
      const int kkb = kbase + tx + 128 * wz;   // lead code base for this thread
      float cearr[8];
#pragma unroll
      for (int ci2 = 0; ci2 < 4; ++ci2) {
        cearr[2 * ci2]     = Ce[kkb + ci2 * 32];
        cearr[2 * ci2 + 1] = Ce[kkb + ci2 * 32 + 16];
      }
#pragma unroll
      for (int ri = 0; ri < 8; ++ri) {
        const float Ar = An[rbase + ty * 8 + ri];   // reload (saves live regs)
#pragma unroll
        for (int ci2 = 0; ci2 < 4; ++ci2) {
          const float d0 = (Ar - 2.0f * acc2[ri][ci2].x) + cearr[2 * ci2];
          if (d0 < best[ri]) { best[ri] = d0; bidx[ri] = kkb + ci2 * 32; }
          const float d1 = (Ar - 2.0f * acc2[ri][ci2].y) + cearr[2 * ci2 + 1];
          if (d1 < best[ri]) { best[ri] = d1; bidx[ri] = kkb + ci2 * 32 + 16; }
          acc2[ri][ci2] = (f32x2){0.f, 0.f};
        }
      }
    }
  }

  // cross-thread argmin per row (tie -> lower absolute index); alias smem
  __syncthreads();                 // compute done; safe to overwrite As/Bs
  float* redd = smem;              // [128][32]
  int*   redi = (int*)(smem + 4096);
#pragma unroll
  for (int ri = 0; ri < 8; ++ri) {
    redd[(ty * 8 + ri) * 32 + (wz * 16 + tx)] = best[ri];
    redi[(ty * 8 + ri) * 32 + (wz * 16 + tx)] = bidx[ri];
  }
  __syncthreads();
  if (t < 128) {
    float bd = redd[t * 32];
    int   bi = redi[t * 32];
    for (int j = 1; j < 32; ++j) {
      const float d  = redd[t * 32 + j];
      const int   i2 = redi[t * 32 + j];
      if (d < bd || (d == bd && i2 < bi)) { bd = d; bi = i2; }
    }
    const int n = rbase + t;
    cand_d[n * 8 + slice] = bd;
    cand_i[n * 8 + slice] = bi;
  }
}

// -------- merge the 8 code-slices (tie -> lower index) --------
__global__ void vq_merge_k(const float* __restrict__ cand_d, const int* __restrict__ cand_i,
                           int* __restrict__ idx_final, float* __restrict__ idxf_out) {
  const int n = blockIdx.x * 256 + threadIdx.x;   // 16384
  float bd = cand_d[n * 8];
  int   bi = cand_i[n * 8];
#pragma unroll
  for (int s = 1; s < 8; ++s) {
    const float d  = cand_d[n * 8 + s];
    const int   i2 = cand_i[n * 8 + s];
    if (d < bd || (d == bd && i2 < bi)) { bd = d; bi = i2; }
  }
  idx_final[n] = bi;
  idxf_out[n] = (float)bi;
}

// -------- gather quantized, write straight-through output, accumulate loss ----
// quantized_st = z + (q - z) in fp32 (matches np rounding; != q exactly).
__launch_bounds__(256)
__global__ void vq_gather_loss_k(const float* __restrict__ z, const float* __restrict__ emb,
                                 const int* __restrict__ idx_final,
                                 float* __restrict__ qout, float* __restrict__ loss_acc) {
  __shared__ float Qs[32 * 260];
  __shared__ int   kidx[32];
  __shared__ float warp_s[4];
  const int t = threadIdx.x;
  const int rbase = blockIdx.x * 32;
  if (t < 32) kidx[t] = idx_final[rbase + t];
  __syncthreads();
  {
    const int r = t >> 3, cp = t & 7;
    const float4* er = (const float4*)(emb + (size_t)kidx[r] * CDIM);
#pragma unroll
    for (int j = 0; j < 8; ++j) {
      const int c4 = cp + j * 8;
      const float4 v = er[c4];
      *(float4*)&Qs[r * 260 + c4 * 4] = v;
    }
  }
  __syncthreads();
  const int b = rbase >> 10, hw0 = rbase & 1023;
  const float* zb = z + (size_t)b * BSTRIDE + hw0;
  float* qb = qout + (size_t)b * BSTRIDE + hw0;
  float s = 0.f;
  const int hwl = t & 31, cg = t >> 5;
  for (int i = 0; i < 32; ++i) {
    const int c = cg * 32 + i;
    const float q  = Qs[hwl * 260 + c];
    const size_t off = (size_t)c * HWS + hwl;
    const float zv = zb[off];
    const float d  = q - zv;
    qb[off] = zv + d;          // straight-through value, np rounding
    s += d * d;
  }
  for (int off = 32; off; off >>= 1) s += __shfl_down(s, off, 64);
  if ((t & 63) == 0) warp_s[t >> 6] = s;
  __syncthreads();
  if (t == 0) atomicAdd(loss_acc, warp_s[0] + warp_s[1] + warp_s[2] + warp_s[3]);
}

__global__ void vq_finalize_k(const float* __restrict__ loss_acc, float* __restrict__ out_loss) {
  const float m = loss_acc[0] * (1.0f / 4194304.0f);
  out_loss[0] = m;          // codebook_loss
  out_loss[1] = 0.25f * m;  // commitment_loss (BETA * same mean)
}

extern "C" void kernel_launch(void* const* d_in, const int* in_sizes, int n_in,
                              void* d_out, int out_size, void* d_ws, size_t ws_size,
                              hipStream_t stream) {
  (void)in_sizes; (void)n_in; (void)out_size; (void)ws_size;
  const float* z   = (const float*)d_in[0];
  const float* emb = (const float*)d_in[1];
  float* out      = (float*)d_out;
  float* q_out    = out;                 // [16,256,32,32]
  float* loss_out = out + 4194304;       // 2 scalars
  float* idxf_out = out + 4194306;       // [16,32,32] as float

  float* ws       = (float*)d_ws;
  float* An       = ws + WS_AN;
  float* Ce       = ws + WS_CE;
  float* cand_d   = ws + WS_CD;
  int*   cand_i   = (int*)(ws + WS_CI);
  int*   idx_fin  = (int*)(ws + WS_IDX);
  float* loss_acc = ws + WS_LOSS;

  hipMemsetAsync(loss_acc, 0, sizeof(float), stream);
  rownorm_z_k<<<64, 256, 0, stream>>>(z, An);
  rownorm_e_k<<<32, 256, 0, stream>>>(emb, Ce);
  vq_argmin_k<<<1024, 512, 0, stream>>>(z, emb, An, Ce, cand_d, cand_i);
  vq_merge_k<<<64, 256, 0, stream>>>(cand_d, cand_i, idx_fin, idxf_out);
  vq_gather_loss_k<<<512, 256, 0, stream>>>(z, emb, idx_fin, q_out, loss_acc);
  vq_finalize_k<<<1, 1, 0, stream>>>(loss_acc, loss_out);
}

// Round 13
// 886.256 us; speedup vs baseline: 1.1012x; 1.0261x over previous
//
#include <hip/hip_runtime.h>

// Problem constants
#define NROWS   16384      // 16*32*32 flattened (b,h,w) rows
#define KCODES  8192
#define CDIM    256
#define HWS     1024       // 32*32
#define BSTRIDE 262144     // 256*1024 floats per batch in z / out

// Workspace layout (float-unit offsets) -- 8 slices
#define WS_AN   0                         // ||x||^2 per row       [16384]
#define WS_CE   16384                     // ||e||^2 per code      [8192]
#define WS_CD   24576                     // cand dist [n*8+slice] [131072]
#define WS_CI   155648                    // cand idx  (int)       [131072]
#define WS_IDX  286720                    // final idx (int)       [16384]
#define WS_LOSS 303104                    // loss accumulator      [1]

typedef float f32x2 __attribute__((ext_vector_type(2)));
typedef float f32x4 __attribute__((ext_vector_type(4)));

// ===== FINAL STRUCTURE (round-11 config, session best: 867us argmin) =====
// v_pk_fma_f32: 2 fp32 FMA/inst, measured sustained ~4.8 cyc (RF-port bound;
// r13 step-major reorder null -> not dep latency). Per-SIMD VALU ~524us.
// LDS pipe (per CU): ~98K ds_read_b128 x 12cyc + writes ~= 530us.
// Both pipes ~equally loaded at ~530us, both measure ~61% busy -> the 867us
// runtime is the dual-pipe floor + 2-wave/SIMD coupling loss.
// Lessons (measured):
//  - launch_bounds VGPR cap ~= 256/min_waves (r10: (256,3)->84 spill;
//    r14: (512,4)->64 spill 204K; keep min_waves=2).
//  - Residency: 8 waves/CU at >64 VGPR in ALL configs; 2x256thr blocks beat
//    1x512thr at same wave count (independent barriers overlap; r15 941us).
//  - Prefetch-early spills (r12: +48 live regs -> 181K scratch).
//  - 16 waves/CU needs <=64 VGPR -> impossible without spilling acc2[8][8].
#define PKFMA_LO(acc, a, b) \
  asm("v_pk_fma_f32 %0, %1, %2, %0 op_sel:[0,0,0] op_sel_hi:[0,1,1]" \
      : "+v"(acc) : "v"(a), "v"(b))
#define PKFMA_HI(acc, a, b) \
  asm("v_pk_fma_f32 %0, %1, %2, %0 op_sel:[1,0,0] op_sel_hi:[1,1,1]" \
      : "+v"(acc) : "v"(a), "v"(b))

// -------- row norms, replicating numpy pairwise_sum order exactly --------
__global__ void rownorm_z_k(const float* __restrict__ z, float* __restrict__ An) {
#pragma clang fp contract(off)
  int n = blockIdx.x * 256 + threadIdx.x;                    // 16384 threads
  const float* base = z + ((size_t)(n >> 10)) * BSTRIDE + (n & 1023);
  float hs[2];
  for (int h = 0; h < 2; ++h) {
    float r[8];
#pragma unroll
    for (int j = 0; j < 8; ++j) { float v = base[(size_t)(h * 128 + j) * HWS]; r[j] = v * v; }
    for (int m = 1; m < 16; ++m) {
#pragma unroll
      for (int j = 0; j < 8; ++j) { float v = base[(size_t)(h * 128 + m * 8 + j) * HWS]; r[j] += v * v; }
    }
    hs[h] = ((r[0] + r[1]) + (r[2] + r[3])) + ((r[4] + r[5]) + (r[6] + r[7]));
  }
  An[n] = hs[0] + hs[1];
}

__global__ void rownorm_e_k(const float* __restrict__ emb, float* __restrict__ Ce) {
#pragma clang fp contract(off)
  int n = blockIdx.x * 256 + threadIdx.x;                    // 8192 threads
  const float* base = emb + (size_t)n * CDIM;
  float hs[2];
  for (int h = 0; h < 2; ++h) {
    float r[8];
#pragma unroll
    for (int j = 0; j < 8; ++j) { float v = base[h * 128 + j]; r[j] = v * v; }
    for (int m = 1; m < 16; ++m) {
#pragma unroll
      for (int j = 0; j < 8; ++j) { float v = base[h * 128 + m * 8 + j]; r[j] += v * v; }
    }
    hs[h] = ((r[0] + r[1]) + (r[2] + r[3])) + ((r[4] + r[5]) + (r[6] + r[7]));
  }
  Ce[n] = hs[0] + hs[1];
}

// -------- fused distance + argmin (round-11 config: session best) -----------
// 1024 blocks = 128 row-tiles (128 rows) x 8 code-slices (1024 codes each).
// slice = bid&7 -> natural XCD affinity (dispatch round-robins bid%8 over the
// 8 XCDs; each XCD's 1MB emb slice stays L2-resident).
// 256 threads (16 tx x 16 ty), 2 blocks/CU resident with independent barrier
// domains. Per-thread 8 rows x 16 codes (acc2[8][8] pk pairs), 32-c
// superchunks, kc 0..3 x sc 0..7.
//   A: As[128 rows][32 c], col=((kg^((row>>3)&7))<<2)|wi; conflict-free reads.
//   B: pair-interleaved [pair][32k][2codes], granule-swizzled by pair&7;
//   one ds_read_b128 = two packed operands. 8x16 micro-tile, g ascending,
//   k3-first 4-k chains, ci-ascending strict-< compares (bit-exact vs ref).
// WRITE_SIZE ~8192 is the no-spill tripwire (r10/r12/r14: 4e6/181K/204K).
__global__ void __launch_bounds__(256, 2)
vq_argmin_k(const float* __restrict__ z, const float* __restrict__ emb,
            const float* __restrict__ An, const float* __restrict__ Ce,
            float* __restrict__ cand_d, int* __restrict__ cand_i) {
  __shared__ float smem[12288];    // 48 KB: As=[0,4096), Bs=[4096,12288)
  float* As = smem;                // [128 rows][32 c], col XOR-swizzled by (row>>3)&7
  float* Bs = smem + 4096;         // [128 pairs][32 k][2 codes], granule-swizzled by pair&7

  const int t  = threadIdx.x;
  const int tx = t & 15;           // code group (16 codes, stride 16)
  const int ty = t >> 4;           // row group (8 consecutive rows)
  const int bid   = blockIdx.x;
  const int slice = bid & 7;       // slice s -> XCD s
  const int tile  = bid >> 3;
  const int rbase = tile * 128;    // never crosses the 1024-hw batch edge
  const int k0    = slice * 1024;

  const float* zb = z + ((size_t)(rbase >> 10)) * BSTRIDE + (rbase & 1023);

  float best[8];
  int   bidx[8];
#pragma unroll
  for (int ri = 0; ri < 8; ++ri) { best[ri] = 3.4028235e38f; bidx[ri] = 0; }

  f32x2 acc2[8][8];                // [ri][ci2]: .x = code tx+32*ci2, .y = +16
#pragma unroll
  for (int ri = 0; ri < 8; ++ri)
#pragma unroll
    for (int j = 0; j < 8; ++j) acc2[ri][j] = (f32x2){0.f, 0.f};

  // staging thread mappings (A identical to rounds 1-15)
  const int a_c   = t >> 4;         // stages c_locals {a_c, a_c+16}, 8 rows each
  const int a_hw  = (t & 15) * 8;   // 8 consecutive rows
  const int a_swr = (t & 15) & 7;   // (row>>3)&7 for all 8 staged rows
  const int a_wi  = a_c & 3;
  const int a_kg1 = a_c >> 2;       // k-group of c1 (c2 = +4)
  const int acol1 = ((a_kg1 ^ a_swr) << 2) | a_wi;        // const per thread
  const int acol2 = (((a_kg1 + 4) ^ a_swr) << 2) | a_wi;
  // B staging: thread loads 16 consecutive c of one emb row, twice (codes
  // b_code and b_code+128), scattering into the pair-interleaved layout.
  const int b_code = t >> 1;        // code 0..127 (pass adds +128)
  const int b_cb   = (t & 1) * 16;  // c_local base 0 or 16
  const int b_p    = ((b_code >> 5) << 4) | (b_code & 15); // pair row 0..63
  const int b_s    = (b_code >> 4) & 1;                    // which half of pair
  const int b_p7   = b_code & 7;                           // == pair&7 (pass-invariant)
  const int b_base = b_p * 64 + ((b_cb >> 1) << 2) + b_s;  // float units; pass1 += 4096

  const int rd_a_sw = ty & 7;
  const int rd_b_sw = tx & 7;       // == pair&7 for all this thread's pair rows
  const int bB      = tx * 64;      // pair-row base (ci2*1024 folds into offset)

  for (int kc = 0; kc < 4; ++kc) {
    const int kbase = k0 + kc * 256;
#pragma unroll 1
    for (int sc = 0; sc < 8; ++sc) {
      // short prefetch: issue just before barrier; regs die at the stores
      const float* zsrc = zb + (size_t)(sc * 32 + a_c) * HWS + a_hw;
      const float4 pa0 = *(const float4*)(zsrc);
      const float4 pa1 = *(const float4*)(zsrc + 4);
      const float4 pa2 = *(const float4*)(zsrc + 16 * HWS);
      const float4 pa3 = *(const float4*)(zsrc + 16 * HWS + 4);
      const float* bsrc0 = emb + (size_t)(kbase + b_code) * CDIM + sc * 32 + b_cb;
      const float* bsrc1 = bsrc0 + (size_t)128 * CDIM;
      const float4 pb0 = *(const float4*)(bsrc0);
      const float4 pb1 = *(const float4*)(bsrc0 + 4);
      const float4 pb2 = *(const float4*)(bsrc0 + 8);
      const float4 pb3 = *(const float4*)(bsrc0 + 12);
      const float4 pb4 = *(const float4*)(bsrc1);
      const float4 pb5 = *(const float4*)(bsrc1 + 4);
      const float4 pb6 = *(const float4*)(bsrc1 + 8);
      const float4 pb7 = *(const float4*)(bsrc1 + 12);

      __syncthreads();                      // barrier A: prior compute done
      {
        // A transpose-store: 16 scalar stores, col const per thread (2-way free)
        const float va0[8] = {pa0.x, pa0.y, pa0.z, pa0.w, pa1.x, pa1.y, pa1.z, pa1.w};
        const float va1[8] = {pa2.x, pa2.y, pa2.z, pa2.w, pa3.x, pa3.y, pa3.z, pa3.w};
#pragma unroll
        for (int j = 0; j < 8; ++j) {
          const int rb = (a_hw + j) << 5;
          As[rb + acol1] = va0[j];
          As[rb + acol2] = va1[j];
        }
        // B pair-scatter, two passes (codes +0 / +128): stride-2 pairs merge
        // into ds_write2_b32. ~4-way conflicts; stores are 1/6 of LDS ops.
        const float bval0[16] = {pb0.x, pb0.y, pb0.z, pb0.w,
                                 pb1.x, pb1.y, pb1.z, pb1.w,
                                 pb2.x, pb2.y, pb2.z, pb2.w,
                                 pb3.x, pb3.y, pb3.z, pb3.w};
        const float bval1[16] = {pb4.x, pb4.y, pb4.z, pb4.w,
                                 pb5.x, pb5.y, pb5.z, pb5.w,
                                 pb6.x, pb6.y, pb6.z, pb6.w,
                                 pb7.x, pb7.y, pb7.z, pb7.w};
#pragma unroll
        for (int i = 0; i < 8; ++i) {
          const int off = b_base + ((i ^ b_p7) << 2);
          Bs[off]            = bval0[2 * i];
          Bs[off + 2]        = bval0[2 * i + 1];
          Bs[off + 4096]     = bval1[2 * i];
          Bs[off + 4096 + 2] = bval1[2 * i + 1];
        }
      }
      __syncthreads();                      // barrier B: staged data visible

      // 8x16 micro-tile over 32 k: 2048 pk_fma, 64 A + 128 B b128 reads.
      // A fragments hoisted (av[8], static-indexed) so B quads stay transient.
#pragma unroll
      for (int g = 0; g < 8; ++g) {
        f32x4 av[8];
#pragma unroll
        for (int ri = 0; ri < 8; ++ri)
          av[ri] = *(const f32x4*)&As[((ty * 8 + ri) << 5) + ((g ^ rd_a_sw) << 2)];
        const int sw0 = ((2 * g) ^ rd_b_sw) << 2;   // granule 2g   (k 4g,4g+1)
        const int sw1 = sw0 ^ 4;                    // granule 2g+1 (k 4g+2,4g+3)
#pragma unroll
        for (int ci2 = 0; ci2 < 8; ++ci2) {
          const f32x4 b0 = *(const f32x4*)&Bs[bB + ci2 * 1024 + sw0];
          const f32x4 b1 = *(const f32x4*)&Bs[bB + ci2 * 1024 + sw1];
          const f32x2 bk0 = __builtin_shufflevector(b0, b0, 0, 1);
          const f32x2 bk1 = __builtin_shufflevector(b0, b0, 2, 3);
          const f32x2 bk2 = __builtin_shufflevector(b1, b1, 0, 1);
          const f32x2 bk3 = __builtin_shufflevector(b1, b1, 2, 3);
#pragma unroll
          for (int ri = 0; ri < 8; ++ri) {
            const f32x2 a01 = __builtin_shufflevector(av[ri], av[ri], 0, 1);
            const f32x2 a23 = __builtin_shufflevector(av[ri], av[ri], 2, 3);
            // 4-k group, k3-first chain: identical lane math all rounds
            PKFMA_HI(acc2[ri][ci2], a23, bk3);
            PKFMA_LO(acc2[ri][ci2], a23, bk2);
            PKFMA_HI(acc2[ri][ci2], a01, bk1);
            PKFMA_LO(acc2[ri][ci2], a01, bk0);
          }
        }
      }
    }

    // fold per kc: dist = (A - 2*dot) + C with np's elementwise fp32 rounding.
    // compare order = ci ascending (ci2 .x then .y) -> identical lowest-index
    // tie semantics; cross-thread/slice merges compare indices explicitly.
    {
      const int kkb = kbase + tx;
      float cearr[16];
#pragma unroll
      for (int ci = 0; ci < 16; ++ci) cearr[ci] = Ce[kkb + ci * 16];
#pragma unroll
      for (int ri = 0; ri < 8; ++ri) {
        const float Ar = An[rbase + ty * 8 + ri];   // reload (saves live regs)
#pragma unroll
        for (int ci2 = 0; ci2 < 8; ++ci2) {
          const float d0 = (Ar - 2.0f * acc2[ri][ci2].x) + cearr[2 * ci2];
          if (d0 < best[ri]) { best[ri] = d0; bidx[ri] = kkb + ci2 * 32; }
          const float d1 = (Ar - 2.0f * acc2[ri][ci2].y) + cearr[2 * ci2 + 1];
          if (d1 < best[ri]) { best[ri] = d1; bidx[ri] = kkb + ci2 * 32 + 16; }
          acc2[ri][ci2] = (f32x2){0.f, 0.f};
        }
      }
    }
  }

  // cross-thread argmin per row (tie -> lower absolute index); alias smem
  __syncthreads();                 // compute done; safe to overwrite As/Bs
  float* redd = smem;              // [128][16]
  int*   redi = (int*)(smem + 2048);
#pragma unroll
  for (int ri = 0; ri < 8; ++ri) {
    redd[(ty * 8 + ri) * 16 + tx] = best[ri];
    redi[(ty * 8 + ri) * 16 + tx] = bidx[ri];
  }
  __syncthreads();
  if (t < 128) {
    float bd = redd[t * 16];
    int   bi = redi[t * 16];
    for (int j = 1; j < 16; ++j) {
      const float d  = redd[t * 16 + j];
      const int   i2 = redi[t * 16 + j];
      if (d < bd || (d == bd && i2 < bi)) { bd = d; bi = i2; }
    }
    const int n = rbase + t;
    cand_d[n * 8 + slice] = bd;
    cand_i[n * 8 + slice] = bi;
  }
}

// -------- merge the 8 code-slices (tie -> lower index) --------
__global__ void vq_merge_k(const float* __restrict__ cand_d, const int* __restrict__ cand_i,
                           int* __restrict__ idx_final, float* __restrict__ idxf_out) {
  const int n = blockIdx.x * 256 + threadIdx.x;   // 16384
  float bd = cand_d[n * 8];
  int   bi = cand_i[n * 8];
#pragma unroll
  for (int s = 1; s < 8; ++s) {
    const float d  = cand_d[n * 8 + s];
    const int   i2 = cand_i[n * 8 + s];
    if (d < bd || (d == bd && i2 < bi)) { bd = d; bi = i2; }
  }
  idx_final[n] = bi;
  idxf_out[n] = (float)bi;
}

// -------- gather quantized, write straight-through output, accumulate loss ----
// quantized_st = z + (q - z) in fp32 (matches np rounding; != q exactly).
__launch_bounds__(256)
__global__ void vq_gather_loss_k(const float* __restrict__ z, const float* __restrict__ emb,
                                 const int* __restrict__ idx_final,
                                 float* __restrict__ qout, float* __restrict__ loss_acc) {
  __shared__ float Qs[32 * 260];
  __shared__ int   kidx[32];
  __shared__ float warp_s[4];
  const int t = threadIdx.x;
  const int rbase = blockIdx.x * 32;
  if (t < 32) kidx[t] = idx_final[rbase + t];
  __syncthreads();
  {
    const int r = t >> 3, cp = t & 7;
    const float4* er = (const float4*)(emb + (size_t)kidx[r] * CDIM);
#pragma unroll
    for (int j = 0; j < 8; ++j) {
      const int c4 = cp + j * 8;
      const float4 v = er[c4];
      *(float4*)&Qs[r * 260 + c4 * 4] = v;
    }
  }
  __syncthreads();
  const int b = rbase >> 10, hw0 = rbase & 1023;
  const float* zb = z + (size_t)b * BSTRIDE + hw0;
  float* qb = qout + (size_t)b * BSTRIDE + hw0;
  float s = 0.f;
  const int hwl = t & 31, cg = t >> 5;
  for (int i = 0; i < 32; ++i) {
    const int c = cg * 32 + i;
    const float q  = Qs[hwl * 260 + c];
    const size_t off = (size_t)c * HWS + hwl;
    const float zv = zb[off];
    const float d  = q - zv;
    qb[off] = zv + d;          // straight-through value, np rounding
    s += d * d;
  }
  for (int off = 32; off; off >>= 1) s += __shfl_down(s, off, 64);
  if ((t & 63) == 0) warp_s[t >> 6] = s;
  __syncthreads();
  if (t == 0) atomicAdd(loss_acc, warp_s[0] + warp_s[1] + warp_s[2] + warp_s[3]);
}

__global__ void vq_finalize_k(const float* __restrict__ loss_acc, float* __restrict__ out_loss) {
  const float m = loss_acc[0] * (1.0f / 4194304.0f);
  out_loss[0] = m;          // codebook_loss
  out_loss[1] = 0.25f * m;  // commitment_loss (BETA * same mean)
}

extern "C" void kernel_launch(void* const* d_in, const int* in_sizes, int n_in,
                              void* d_out, int out_size, void* d_ws, size_t ws_size,
                              hipStream_t stream) {
  (void)in_sizes; (void)n_in; (void)out_size; (void)ws_size;
  const float* z   = (const float*)d_in[0];
  const float* emb = (const float*)d_in[1];
  float* out      = (float*)d_out;
  float* q_out    = out;                 // [16,256,32,32]
  float* loss_out = out + 4194304;       // 2 scalars
  float* idxf_out = out + 4194306;       // [16,32,32] as float

  float* ws       = (float*)d_ws;
  float* An       = ws + WS_AN;
  float* Ce       = ws + WS_CE;
  float* cand_d   = ws + WS_CD;
  int*   cand_i   = (int*)(ws + WS_CI);
  int*   idx_fin  = (int*)(ws + WS_IDX);
  float* loss_acc = ws + WS_LOSS;

  hipMemsetAsync(loss_acc, 0, sizeof(float), stream);
  rownorm_z_k<<<64, 256, 0, stream>>>(z, An);
  rownorm_e_k<<<32, 256, 0, stream>>>(emb, Ce);
  vq_argmin_k<<<1024, 256, 0, stream>>>(z, emb, An, Ce, cand_d, cand_i);
  vq_merge_k<<<64, 256, 0, stream>>>(cand_d, cand_i, idx_fin, idxf_out);
  vq_gather_loss_k<<<512, 256, 0, stream>>>(z, emb, idx_fin, q_out, loss_acc);
  vq_finalize_k<<<1, 1, 0, stream>>>(loss_acc, loss_out);
}